// Round 15
// baseline (242.844 us; speedup 1.0000x reference)
//
#include <hip/hip_runtime.h>
#include <hip/hip_bf16.h>

typedef unsigned int u32;
typedef unsigned short u16;
typedef __attribute__((ext_vector_type(8))) short short8;
typedef __attribute__((ext_vector_type(4))) float f32x4;

#define NLOC 8192      // B*HWC
#define LCTX 32
#define NH   8

__device__ __forceinline__ float bl(u32 u){ return __uint_as_float(u << 16); }
__device__ __forceinline__ float bh(u32 u){ return __uint_as_float(u & 0xffff0000u); }
__device__ __forceinline__ u16 f2b(float f){
  u32 u = __float_as_uint(f);
  return (u16)((u + 0x7fffu + ((u >> 16) & 1u)) >> 16);
}
// HW packed f32->bf16 (RTNE — bit-identical to f2b).
__device__ __forceinline__ u32 pk2(float a, float b){
  u32 r;
  asm("v_cvt_pk_bf16_f32 %0, %1, %2" : "=v"(r) : "v"(a), "v"(b));
  return r;
}
#define MFMA16(a, b, c) __builtin_amdgcn_mfma_f32_16x16x32_bf16(a, b, c, 0, 0, 0)

// K0 v2: weights -> bf16 in MFMA B-FRAGMENT ORDER (unchanged from round 13).
__global__ __launch_bounds__(256) void k0_prep(const float* __restrict__ kw,
                                               const float* __restrict__ vw,
                                               u16* __restrict__ kwp,
                                               u16* __restrict__ vwp){
  int i = blockIdx.x * 256 + threadIdx.x;      // 262144, i = o*512 + c
  int o = i >> 9, c = i & 511;
  {
    int h = o >> 6, rem = o & 63;
    int ks = rem >> 5, kg = (rem >> 3) & 3, j = rem & 7;
    int cb = c >> 4, l_lo = c & 15;
    int lane = kg * 16 + l_lo;
    kwp[(((h * 32 + cb) * 2 + ks) * 64 + lane) * 8 + j] = f2b(kw[i]);
  }
  {
    int h = o >> 6, rem = o & 63;
    int wd = rem >> 4, l_lo = rem & 15;
    int ks = c >> 5, cr = c & 31, kg = cr >> 3, j = cr & 7;
    int lane = kg * 16 + l_lo;
    vwp[(((h * 4 + wd) * 16 + ks) * 64 + lane) * 8 + j] = f2b(vw[i]);
  }
}

// KLN: LayerNorm -> qln bf16 [loc][512]. (unchanged)
__global__ __launch_bounds__(256) void kln(const float* __restrict__ q,
                                           const float* __restrict__ lng,
                                           const float* __restrict__ lnb,
                                           u16* __restrict__ qln){
  int tid = threadIdx.x;
  int lane = tid & 63, wv = tid >> 6;
  long bn = (long)blockIdx.x * 4 + wv;
  const float4* qr = (const float4*)(q + bn * 512);
  float4 v0 = qr[lane * 2], v1 = qr[lane * 2 + 1];
  float s  = v0.x + v0.y + v0.z + v0.w + v1.x + v1.y + v1.z + v1.w;
  float s2 = v0.x*v0.x + v0.y*v0.y + v0.z*v0.z + v0.w*v0.w
           + v1.x*v1.x + v1.y*v1.y + v1.z*v1.z + v1.w*v1.w;
#pragma unroll
  for (int d = 1; d < 64; d <<= 1){ s += __shfl_xor(s, d); s2 += __shfl_xor(s2, d); }
  float mu = s * (1.f / 512.f);
  float rstd = rsqrtf(s2 * (1.f / 512.f) - mu * mu + 1e-5f);
  int c = lane * 8;
  float4 g0 = *(const float4*)&lng[c], g1 = *(const float4*)&lng[c + 4];
  float4 b0 = *(const float4*)&lnb[c], b1 = *(const float4*)&lnb[c + 4];
  uint4 st;
  st.x = pk2((v0.x - mu) * rstd * g0.x + b0.x, (v0.y - mu) * rstd * g0.y + b0.y);
  st.y = pk2((v0.z - mu) * rstd * g0.z + b0.z, (v0.w - mu) * rstd * g0.w + b0.w);
  st.z = pk2((v1.x - mu) * rstd * g1.x + b1.x, (v1.y - mu) * rstd * g1.y + b1.y);
  st.w = pk2((v1.z - mu) * rstd * g1.z + b1.z, (v1.w - mu) * rstd * g1.w + b1.w);
  *(uint4*)&qln[bn * 512 + c] = st;
}

// K1g v4 (unchanged from round 13): packed-B 1KB coalesced loads.
#define K1G_QS   2048
#define K1G_WT   (16 * 272)
#define K1G_LDS  (K1G_QS + 4 * K1G_WT)
__global__ __launch_bounds__(256) void k1g(const u16* __restrict__ qln,
                                           const u16* __restrict__ kwp,
                                           u16* __restrict__ kqw,
                                           int base){
  extern __shared__ char smem[];
  char* qs = smem;
  int tid = threadIdx.x;
  int lane = tid & 63, w = tid >> 6;
  char* wt = smem + K1G_QS + w * K1G_WT;
  int h = blockIdx.y;
  long t0 = (long)blockIdx.x * 16;
  long g0 = (long)base + t0;
  if (tid < 128){
    int t = tid >> 3, part = tid & 7;
    const char* src = (const char*)(qln + (g0 + t) * 512 + h * 64) + part * 16;
    uint4 a = *(const uint4*)src;
    *(uint4*)(qs + t * 128 + ((part * 16) ^ ((t & 7) << 4))) = a;
  }
  __syncthreads();
  int l_lo = lane & 15, kg = lane >> 4;
  short8 afr[2];
#pragma unroll
  for (int ks = 0; ks < 2; ks++)
    afr[ks] = *(const short8*)(qs + l_lo * 128 +
              ((ks * 64 + kg * 16) ^ ((l_lo & 7) << 4)));
#pragma unroll
  for (int nt = 0; nt < 8; nt++){
    int cb = w * 8 + nt;
    const u16* bp = &kwp[((h * 32 + cb) * 2 * 64 + lane) * 8];
    short8 bfr0 = *(const short8*)bp;              // ks=0
    short8 bfr1 = *(const short8*)(bp + 512);      // ks=1
    f32x4 acc = {0.f, 0.f, 0.f, 0.f};
    acc = MFMA16(afr[0], bfr0, acc);
    acc = MFMA16(afr[1], bfr1, acc);
#pragma unroll
    for (int r = 0; r < 4; r++)
      *(u16*)(wt + (kg * 4 + r) * 272 + (nt * 16 + l_lo) * 2) = f2b(acc[r]);
  }
  {
    int t = lane >> 2, part = lane & 3;
#pragma unroll
    for (int j = 0; j < 4; j++){
      uint4 v = *(const uint4*)(wt + t * 272 + part * 64 + j * 16);
      *(uint4*)&kqw[((t0 + t) * 8 + h) * 512 + w * 128 + part * 32 + j * 8] = v;
    }
  }
}

// K2m v7 = round-13 compute EXACTLY (1 loc/block, 36KB LDS, 4 blocks/CU);
// only change: wctx written OUT-OF-PLACE in k3g A-FRAGMENT-PACKED order.
// Write pattern is 4x16B scattered per thread either way -> neutral for k2m.
//   wfp[(((g*8+h)*16 + ks)*64 + kg*16 + tl)*8 + j],
//   g = lc>>4, tl = lc&15, ks = co>>2, kg = co&3, j = 0..7.
__global__ __launch_bounds__(256, 4) void k2m(const float* __restrict__ ctx,
                                              const u16* __restrict__ kqr,
                                              u16* __restrict__ wfp,
                                              int base){
  __shared__ char ctxs[32 * 1024];          // bf16 [32 l][1024 B], XOR-swizzled
  __shared__ float smat4[4 * 16 * 8];       // per-wave score partials [w][l16][h]
  __shared__ __align__(16) float swb[32 * 8]; // softmax weights [l][h]
  int tid = threadIdx.x;
  int lane = tid & 63, w = tid >> 6;
  long bn = (long)base + blockIdx.x;
  const float4* cp = (const float4*)(ctx + bn * (32 * 512));
  const u16* kqg = kqr + (long)blockIdx.x * 4096;
  float4 rv[16];
#pragma unroll
  for (int i = 0; i < 16; i++) rv[i] = cp[i * 256 + tid];
#pragma unroll
  for (int i = 0; i < 16; i++){
    int e0 = (i * 256 + tid) * 4;
    int l = e0 >> 9, col = e0 & 511;
    uint2 pk; pk.x = pk2(rv[i].x, rv[i].y); pk.y = pk2(rv[i].z, rv[i].w);
    *(uint2*)(ctxs + l * 1024 + ((col * 2) ^ ((l & 7) << 4))) = pk;
  }
  __syncthreads();
  {
    int l_lo = lane & 15, kg = lane >> 4;
    int lset = w >> 1, kk = w & 1;
    int trow = lset * 16 + l_lo;
    int hb = lane & 7;
    f32x4 acc = {0.f, 0.f, 0.f, 0.f};
#pragma unroll
    for (int s = 0; s < 8; s++){
      int cbyte = kk * 512 + s * 64 + kg * 16;
      short8 a = *(const short8*)(ctxs + trow * 1024 + (cbyte ^ ((trow & 7) << 4)));
      short8 b = *(const short8*)&kqg[hb * 512 + (cbyte >> 1)];
      acc = MFMA16(a, b, acc);
    }
    if (l_lo < 8){
#pragma unroll
      for (int r = 0; r < 4; r++)
        smat4[w * 128 + (kg * 4 + r) * 8 + l_lo] = acc[r];
    }
  }
  __syncthreads();
  if (tid < 8){
    float s[32];
#pragma unroll
    for (int j = 0; j < 32; j++){
      int lset = j >> 4, jl = j & 15;
      s[j] = smat4[(lset * 2) * 128 + jl * 8 + tid]
           + smat4[(lset * 2 + 1) * 128 + jl * 8 + tid];
    }
    float mx = s[0];
#pragma unroll
    for (int j = 1; j < 32; j++) mx = fmaxf(mx, s[j]);
    float S = 0.f;
#pragma unroll
    for (int j = 0; j < 32; j++){ s[j] = __expf(s[j] - mx); S += s[j]; }
    float inv = 1.f / S;
#pragma unroll
    for (int j = 0; j < 32; j++) swb[j * 8 + tid] = s[j] * inv;
  }
  __syncthreads();
  {
    int lh = (lane >> 4) & 1, hq = lane >> 5;
    int co = (lane & 15) | (w << 4);
    int cb = co * 16;
    float acc[4][8];
#pragma unroll
    for (int hh = 0; hh < 4; hh++)
#pragma unroll
      for (int cc = 0; cc < 8; cc++) acc[hh][cc] = 0.f;
#pragma unroll 4
    for (int j = 0; j < 16; j++){
      int l = lh * 16 + j;
      uint4 cv = *(const uint4*)(ctxs + l * 1024 + (cb ^ ((l & 7) << 4)));
      float4 wv = *(const float4*)&swb[l * 8 + hq * 4];
      float wf[4] = { wv.x, wv.y, wv.z, wv.w };
      float cf[8] = { bl(cv.x), bh(cv.x), bl(cv.y), bh(cv.y),
                      bl(cv.z), bh(cv.z), bl(cv.w), bh(cv.w) };
#pragma unroll
      for (int hh = 0; hh < 4; hh++)
#pragma unroll
        for (int cc = 0; cc < 8; cc++)
          acc[hh][cc] += wf[hh] * cf[cc];
    }
#pragma unroll
    for (int hh = 0; hh < 4; hh++)
#pragma unroll
      for (int cc = 0; cc < 8; cc++)
        acc[hh][cc] += __shfl_xor(acc[hh][cc], 16);
    if (!lh){
      long lc = blockIdx.x;
      long g = lc >> 4;
      int tl = (int)(lc & 15);
      int ks = co >> 2, kg = co & 3;
#pragma unroll
      for (int hh = 0; hh < 4; hh++){
        int h = hq * 4 + hh;
        uint4 st;
        st.x = pk2(acc[hh][0], acc[hh][1]); st.y = pk2(acc[hh][2], acc[hh][3]);
        st.z = pk2(acc[hh][4], acc[hh][5]); st.w = pk2(acc[hh][6], acc[hh][7]);
        *(uint4*)&wfp[(((g * 8 + h) * 16 + ks) * 64 + kg * 16 + tl) * 8] = st;
      }
    }
  }
}

// K3g v6: NO LDS, NO barrier. A (wctx) AND B (v_w) both fragment-packed ->
// per ks one 1KB coalesced wave-load each. Same ks order as v5 ->
// bit-identical out. Occupancy VGPR-bound (deep latency tolerance).
__global__ __launch_bounds__(256) void k3g(const u16* __restrict__ wfp,
                                           const u16* __restrict__ vwp,
                                           const float* __restrict__ vb,
                                           float* __restrict__ out,
                                           int base){
  int tid = threadIdx.x;
  int lane = tid & 63, w = tid >> 6;
  int h = blockIdx.y;
  long g = blockIdx.x;                      // 16-loc group
  long t0 = g * 16;
  int l_lo = lane & 15, kg = lane >> 4;
  const u16* ap = &wfp[((g * 8 + h) * 16) * 512 + lane * 8];
  const u16* bp = &vwp[((h * 4 + w) * 16 * 64 + lane) * 8];
  f32x4 acc = {0.f, 0.f, 0.f, 0.f};
#pragma unroll
  for (int ks = 0; ks < 16; ks++){
    short8 a = *(const short8*)(ap + ks * 512);   // 1KB coalesced
    short8 b = *(const short8*)(bp + ks * 512);   // 1KB coalesced
    acc = MFMA16(a, b, acc);
  }
  {
    float vbn = vb[h * 64 + w * 16 + l_lo];
#pragma unroll
    for (int r = 0; r < 4; r++){
      int t = kg * 4 + r;
      long loc = (long)base + t0 + t;
      long b = loc >> 12, n = loc & 4095;
      out[(((b * 8 + h) * 4096 + n) << 6) + w * 16 + l_lo] = acc[r] + vbn;
    }
  }
}

extern "C" void kernel_launch(void* const* d_in, const int* in_sizes, int n_in,
                              void* d_out, int out_size, void* d_ws, size_t ws_size,
                              hipStream_t stream){
  const float* q   = (const float*)d_in[0];
  const float* ctx = (const float*)d_in[1];
  const float* kw  = (const float*)d_in[2];
  // d_in[3] = k_b : cancels in softmax, unused
  const float* vw  = (const float*)d_in[4];
  const float* vb  = (const float*)d_in[5];
  const float* lng = (const float*)d_in[6];
  const float* lnb = (const float*)d_in[7];
  float* out = (float*)d_out;

  u16* kwp = (u16*)d_ws;                 // 512 KB (k_w, fragment-packed)
  u16* vwp = kwp + 512 * 512;            // 512 KB (v_w, fragment-packed)
  u16* qln = vwp + 512 * 512;            // 8 MB (LN'd q, bf16)
  u16* kqw = qln + (long)NLOC * 512;     // CH * 8 KB (kq)

  size_t resv = 2u * 512 * 1024 + (size_t)NLOC * 1024;
  size_t avail = ws_size > resv ? ws_size - resv : 0;
  long CH = (long)(avail / 16384);       // 8 KB kq + 8 KB packed wctx per loc
  if (CH > NLOC) CH = NLOC;
  CH &= ~63L;
  if (CH < 64) CH = 64;
  u16* wfp = kqw + CH * 4096;            // CH * 8 KB (wctx, A-frag packed)

  (void)hipFuncSetAttribute((const void*)k1g,
                      hipFuncAttributeMaxDynamicSharedMemorySize, K1G_LDS);

  hipLaunchKernelGGL(k0_prep, dim3(1024), dim3(256), 0, stream, kw, vw, kwp, vwp);
  hipLaunchKernelGGL(kln, dim3(NLOC / 4), dim3(256), 0, stream, q, lng, lnb, qln);
  for (long base = 0; base < NLOC; base += CH){
    long M = NLOC - base; if (M > CH) M = CH;
    hipLaunchKernelGGL(k1g, dim3(M / 16, 8), dim3(256), K1G_LDS, stream,
                       qln, kwp, kqw, (int)base);
    hipLaunchKernelGGL(k2m, dim3(M), dim3(256), 0, stream, ctx, kqw, wfp, (int)base);
    hipLaunchKernelGGL(k3g, dim3(M / 16, 8), dim3(256), 0, stream,
                       wfp, vwp, vb, out, (int)base);
  }
}

// Round 16
// 194.433 us; speedup vs baseline: 1.2490x; 1.2490x over previous
//
#include <hip/hip_runtime.h>
#include <hip/hip_bf16.h>

typedef unsigned int u32;
typedef unsigned short u16;
typedef __attribute__((ext_vector_type(8))) short short8;
typedef __attribute__((ext_vector_type(4))) float f32x4;

#define NLOC 8192      // B*HWC
#define LCTX 32
#define NH   8

__device__ __forceinline__ float bl(u32 u){ return __uint_as_float(u << 16); }
__device__ __forceinline__ float bh(u32 u){ return __uint_as_float(u & 0xffff0000u); }
__device__ __forceinline__ u16 f2b(float f){
  u32 u = __float_as_uint(f);
  return (u16)((u + 0x7fffu + ((u >> 16) & 1u)) >> 16);
}
// HW packed f32->bf16 (RTNE — bit-identical to f2b).
__device__ __forceinline__ u32 pk2(float a, float b){
  u32 r;
  asm("v_cvt_pk_bf16_f32 %0, %1, %2" : "=v"(r) : "v"(a), "v"(b));
  return r;
}
#define MFMA16(a, b, c) __builtin_amdgcn_mfma_f32_16x16x32_bf16(a, b, c, 0, 0, 0)

// K0 v2: weights -> bf16 in MFMA B-FRAGMENT ORDER, so each wave B-load is
// one contiguous 1KB line (was 16 scattered 16B reads 1KB apart).
__global__ __launch_bounds__(256) void k0_prep(const float* __restrict__ kw,
                                               const float* __restrict__ vw,
                                               u16* __restrict__ kwp,
                                               u16* __restrict__ vwp){
  int i = blockIdx.x * 256 + threadIdx.x;      // 262144, i = o*512 + c
  int o = i >> 9, c = i & 511;
  {
    int h = o >> 6, rem = o & 63;
    int ks = rem >> 5, kg = (rem >> 3) & 3, j = rem & 7;
    int cb = c >> 4, l_lo = c & 15;
    int lane = kg * 16 + l_lo;
    kwp[(((h * 32 + cb) * 2 + ks) * 64 + lane) * 8 + j] = f2b(kw[i]);
  }
  {
    int h = o >> 6, rem = o & 63;
    int wd = rem >> 4, l_lo = rem & 15;
    int ks = c >> 5, cr = c & 31, kg = cr >> 3, j = cr & 7;
    int lane = kg * 16 + l_lo;
    vwp[(((h * 4 + wd) * 16 + ks) * 64 + lane) * 8 + j] = f2b(vw[i]);
  }
}

// KLN: LayerNorm -> qln bf16 [loc][512]. 1 wave per loc, 4 locs/block.
__global__ __launch_bounds__(256) void kln(const float* __restrict__ q,
                                           const float* __restrict__ lng,
                                           const float* __restrict__ lnb,
                                           u16* __restrict__ qln){
  int tid = threadIdx.x;
  int lane = tid & 63, wv = tid >> 6;
  long bn = (long)blockIdx.x * 4 + wv;
  const float4* qr = (const float4*)(q + bn * 512);
  float4 v0 = qr[lane * 2], v1 = qr[lane * 2 + 1];
  float s  = v0.x + v0.y + v0.z + v0.w + v1.x + v1.y + v1.z + v1.w;
  float s2 = v0.x*v0.x + v0.y*v0.y + v0.z*v0.z + v0.w*v0.w
           + v1.x*v1.x + v1.y*v1.y + v1.z*v1.z + v1.w*v1.w;
#pragma unroll
  for (int d = 1; d < 64; d <<= 1){ s += __shfl_xor(s, d); s2 += __shfl_xor(s2, d); }
  float mu = s * (1.f / 512.f);
  float rstd = rsqrtf(s2 * (1.f / 512.f) - mu * mu + 1e-5f);
  int c = lane * 8;
  float4 g0 = *(const float4*)&lng[c], g1 = *(const float4*)&lng[c + 4];
  float4 b0 = *(const float4*)&lnb[c], b1 = *(const float4*)&lnb[c + 4];
  uint4 st;
  st.x = pk2((v0.x - mu) * rstd * g0.x + b0.x, (v0.y - mu) * rstd * g0.y + b0.y);
  st.y = pk2((v0.z - mu) * rstd * g0.z + b0.z, (v0.w - mu) * rstd * g0.w + b0.w);
  st.z = pk2((v1.x - mu) * rstd * g1.x + b1.x, (v1.y - mu) * rstd * g1.y + b1.y);
  st.w = pk2((v1.z - mu) * rstd * g1.z + b1.z, (v1.w - mu) * rstd * g1.w + b1.w);
  *(uint4*)&qln[bn * 512 + c] = st;
}

// K1g v4: 16 locs/block, wave-private out tile, packed-B 1KB coalesced loads.
#define K1G_QS   2048
#define K1G_WT   (16 * 272)
#define K1G_LDS  (K1G_QS + 4 * K1G_WT)
__global__ __launch_bounds__(256) void k1g(const u16* __restrict__ qln,
                                           const u16* __restrict__ kwp,
                                           u16* __restrict__ kqw,
                                           int base){
  extern __shared__ char smem[];
  char* qs = smem;
  int tid = threadIdx.x;
  int lane = tid & 63, w = tid >> 6;
  char* wt = smem + K1G_QS + w * K1G_WT;
  int h = blockIdx.y;
  long t0 = (long)blockIdx.x * 16;
  long g0 = (long)base + t0;
  if (tid < 128){
    int t = tid >> 3, part = tid & 7;
    const char* src = (const char*)(qln + (g0 + t) * 512 + h * 64) + part * 16;
    uint4 a = *(const uint4*)src;
    *(uint4*)(qs + t * 128 + ((part * 16) ^ ((t & 7) << 4))) = a;
  }
  __syncthreads();
  int l_lo = lane & 15, kg = lane >> 4;
  short8 afr[2];
#pragma unroll
  for (int ks = 0; ks < 2; ks++)
    afr[ks] = *(const short8*)(qs + l_lo * 128 +
              ((ks * 64 + kg * 16) ^ ((l_lo & 7) << 4)));
#pragma unroll
  for (int nt = 0; nt < 8; nt++){
    int cb = w * 8 + nt;
    const u16* bp = &kwp[((h * 32 + cb) * 2 * 64 + lane) * 8];
    short8 bfr0 = *(const short8*)bp;              // ks=0
    short8 bfr1 = *(const short8*)(bp + 512);      // ks=1
    f32x4 acc = {0.f, 0.f, 0.f, 0.f};
    acc = MFMA16(afr[0], bfr0, acc);
    acc = MFMA16(afr[1], bfr1, acc);
#pragma unroll
    for (int r = 0; r < 4; r++)
      *(u16*)(wt + (kg * 4 + r) * 272 + (nt * 16 + l_lo) * 2) = f2b(acc[r]);
  }
  {
    int t = lane >> 2, part = lane & 3;
#pragma unroll
    for (int j = 0; j < 4; j++){
      uint4 v = *(const uint4*)(wt + t * 272 + part * 64 + j * 16);
      *(uint4*)&kqw[((t0 + t) * 8 + h) * 512 + w * 128 + part * 32 + j * 8] = v;
    }
  }
}

// K2m v3 (round-13 best): LDS-lean attention core, in-place kq->wctx.
__global__ __launch_bounds__(256, 4) void k2m(const float* __restrict__ ctx,
                                              u16* __restrict__ kqw,
                                              int base){
  __shared__ char ctxs[32 * 1024];          // bf16 [32 l][1024 B], XOR-swizzled
  __shared__ float smat4[4 * 16 * 8];       // per-wave score partials [w][l16][h]
  __shared__ __align__(16) float swb[32 * 8]; // softmax weights [l][h]
  int tid = threadIdx.x;
  int lane = tid & 63, w = tid >> 6;
  long bn = (long)base + blockIdx.x;
  const float4* cp = (const float4*)(ctx + bn * (32 * 512));
  const u16* kqg = kqw + (long)blockIdx.x * 4096;
  float4 rv[16];
#pragma unroll
  for (int i = 0; i < 16; i++) rv[i] = cp[i * 256 + tid];
#pragma unroll
  for (int i = 0; i < 16; i++){
    int e0 = (i * 256 + tid) * 4;
    int l = e0 >> 9, col = e0 & 511;
    uint2 pk; pk.x = pk2(rv[i].x, rv[i].y); pk.y = pk2(rv[i].z, rv[i].w);
    *(uint2*)(ctxs + l * 1024 + ((col * 2) ^ ((l & 7) << 4))) = pk;
  }
  __syncthreads();
  {
    int l_lo = lane & 15, kg = lane >> 4;
    int lset = w >> 1, kk = w & 1;
    int trow = lset * 16 + l_lo;
    int hb = lane & 7;
    f32x4 acc = {0.f, 0.f, 0.f, 0.f};
#pragma unroll
    for (int s = 0; s < 8; s++){
      int cbyte = kk * 512 + s * 64 + kg * 16;
      short8 a = *(const short8*)(ctxs + trow * 1024 + (cbyte ^ ((trow & 7) << 4)));
      short8 b = *(const short8*)&kqg[hb * 512 + (cbyte >> 1)];
      acc = MFMA16(a, b, acc);
    }
    if (l_lo < 8){
#pragma unroll
      for (int r = 0; r < 4; r++)
        smat4[w * 128 + (kg * 4 + r) * 8 + l_lo] = acc[r];
    }
  }
  __syncthreads();
  if (tid < 8){
    float s[32];
#pragma unroll
    for (int j = 0; j < 32; j++){
      int lset = j >> 4, jl = j & 15;
      s[j] = smat4[(lset * 2) * 128 + jl * 8 + tid]
           + smat4[(lset * 2 + 1) * 128 + jl * 8 + tid];
    }
    float mx = s[0];
#pragma unroll
    for (int j = 1; j < 32; j++) mx = fmaxf(mx, s[j]);
    float S = 0.f;
#pragma unroll
    for (int j = 0; j < 32; j++){ s[j] = __expf(s[j] - mx); S += s[j]; }
    float inv = 1.f / S;
#pragma unroll
    for (int j = 0; j < 32; j++) swb[j * 8 + tid] = s[j] * inv;
  }
  __syncthreads();
  {
    int lh = (lane >> 4) & 1, hq = lane >> 5;
    int co = (lane & 15) | (w << 4);
    int cb = co * 16;
    float acc[4][8];
#pragma unroll
    for (int hh = 0; hh < 4; hh++)
#pragma unroll
      for (int cc = 0; cc < 8; cc++) acc[hh][cc] = 0.f;
#pragma unroll 4
    for (int j = 0; j < 16; j++){
      int l = lh * 16 + j;
      uint4 cv = *(const uint4*)(ctxs + l * 1024 + (cb ^ ((l & 7) << 4)));
      float4 wv = *(const float4*)&swb[l * 8 + hq * 4];
      float wf[4] = { wv.x, wv.y, wv.z, wv.w };
      float cf[8] = { bl(cv.x), bh(cv.x), bl(cv.y), bh(cv.y),
                      bl(cv.z), bh(cv.z), bl(cv.w), bh(cv.w) };
#pragma unroll
      for (int hh = 0; hh < 4; hh++)
#pragma unroll
        for (int cc = 0; cc < 8; cc++)
          acc[hh][cc] += wf[hh] * cf[cc];
    }
#pragma unroll
    for (int hh = 0; hh < 4; hh++)
#pragma unroll
      for (int cc = 0; cc < 8; cc++)
        acc[hh][cc] += __shfl_xor(acc[hh][cc], 16);
    if (!lh){
      u16* wp = kqw + (long)blockIdx.x * 4096;
#pragma unroll
      for (int hh = 0; hh < 4; hh++){
        uint4 st;
        st.x = pk2(acc[hh][0], acc[hh][1]); st.y = pk2(acc[hh][2], acc[hh][3]);
        st.z = pk2(acc[hh][4], acc[hh][5]); st.w = pk2(acc[hh][6], acc[hh][7]);
        *(uint4*)&wp[(hq * 4 + hh) * 512 + co * 8] = st;
      }
    }
  }
}

// K3g v5 (round-13 best): LDS-staged A (16 locs/block) + packed-B loads.
#define K3G_LDS (16 * 1024)
__global__ __launch_bounds__(256) void k3g(const u16* __restrict__ wctx,
                                           const u16* __restrict__ vwp,
                                           const float* __restrict__ vb,
                                           float* __restrict__ out,
                                           int base){
  extern __shared__ char smem[];            // [16 rows][1024 B] swizzled
  int tid = threadIdx.x;
  int lane = tid & 63, w = tid >> 6;
  int h = blockIdx.y;
  long t0 = (long)blockIdx.x * 16;
  {
    int tr = tid >> 4, seg = tid & 15;
    const char* src = (const char*)&wctx[((t0 + tr) * 8 + h) * 512];
    int sw = (tr & 7) << 4;
#pragma unroll
    for (int j = 0; j < 4; j++){
      int off = seg * 64 + j * 16;
      *(uint4*)(smem + tr * 1024 + (off ^ sw)) = *(const uint4*)(src + off);
    }
  }
  __syncthreads();
  int l_lo = lane & 15, kg = lane >> 4;
  const char* arow = smem + l_lo * 1024;
  int sw = (l_lo & 7) << 4;
  const u16* bp = &vwp[((h * 4 + w) * 16 * 64 + lane) * 8];
  f32x4 acc = {0.f, 0.f, 0.f, 0.f};
#pragma unroll 4
  for (int ks = 0; ks < 16; ks++){
    short8 a = *(const short8*)(arow + ((ks * 64 + kg * 16) ^ sw));
    short8 b = *(const short8*)(bp + ks * 512);   // 1KB coalesced line / wave
    acc = MFMA16(a, b, acc);
  }
  {
    float vbn = vb[h * 64 + w * 16 + l_lo];
#pragma unroll
    for (int r = 0; r < 4; r++){
      int t = kg * 4 + r;
      long loc = (long)base + t0 + t;
      long b = loc >> 12, n = loc & 4095;
      out[(((b * 8 + h) * 4096 + n) << 6) + w * 16 + l_lo] = acc[r] + vbn;
    }
  }
}

extern "C" void kernel_launch(void* const* d_in, const int* in_sizes, int n_in,
                              void* d_out, int out_size, void* d_ws, size_t ws_size,
                              hipStream_t stream){
  const float* q   = (const float*)d_in[0];
  const float* ctx = (const float*)d_in[1];
  const float* kw  = (const float*)d_in[2];
  // d_in[3] = k_b : cancels in softmax, unused
  const float* vw  = (const float*)d_in[4];
  const float* vb  = (const float*)d_in[5];
  const float* lng = (const float*)d_in[6];
  const float* lnb = (const float*)d_in[7];
  float* out = (float*)d_out;

  u16* kwp = (u16*)d_ws;                 // 512 KB (k_w, fragment-packed)
  u16* vwp = kwp + 512 * 512;            // 512 KB (v_w, fragment-packed)
  u16* qln = vwp + 512 * 512;            // 8 MB (LN'd q, bf16)
  u16* kqw = qln + (long)NLOC * 512;     // CH * 8 KB (kq, then wctx in place)

  size_t resv = 2u * 512 * 1024 + (size_t)NLOC * 1024;
  size_t avail = ws_size > resv ? ws_size - resv : 0;
  long CH = (long)(avail / 8192);
  if (CH > NLOC) CH = NLOC;
  CH &= ~63L;
  if (CH < 64) CH = 64;

  (void)hipFuncSetAttribute((const void*)k1g,
                      hipFuncAttributeMaxDynamicSharedMemorySize, K1G_LDS);
  (void)hipFuncSetAttribute((const void*)k3g,
                      hipFuncAttributeMaxDynamicSharedMemorySize, K3G_LDS);

  hipLaunchKernelGGL(k0_prep, dim3(1024), dim3(256), 0, stream, kw, vw, kwp, vwp);
  hipLaunchKernelGGL(kln, dim3(NLOC / 4), dim3(256), 0, stream, q, lng, lnb, qln);
  for (long base = 0; base < NLOC; base += CH){
    long M = NLOC - base; if (M > CH) M = CH;
    hipLaunchKernelGGL(k1g, dim3(M / 16, 8), dim3(256), K1G_LDS, stream,
                       qln, kwp, kqw, (int)base);
    hipLaunchKernelGGL(k2m, dim3(M), dim3(256), 0, stream, ctx, kqw, (int)base);
    hipLaunchKernelGGL(k3g, dim3(M / 16, 8), dim3(256), K3G_LDS, stream,
                       kqw, vwp, vb, out, (int)base);
  }
}